// Round 9
// baseline (443.332 us; speedup 1.0000x reference)
//
#include <hip/hip_runtime.h>
#include <hip/hip_bf16.h>

// ---------------- types ----------------
typedef __attribute__((ext_vector_type(8))) short s16x8;    // 8 bf16 in 4 VGPRs
typedef __attribute__((ext_vector_type(4))) float f32x4;
typedef __attribute__((ext_vector_type(16))) float f32x16;  // 32x32 MFMA accumulator

// B=4, C=256, H=W=160, padded spatial 162, S dims 161, N=512, REID=128

__device__ __forceinline__ void async_ld16(const void* g, void* l) {
  __builtin_amdgcn_global_load_lds(
      (const __attribute__((address_space(1))) void*)g,
      (__attribute__((address_space(3))) void*)l, 16, 0, 0);
}

// ---------------- 0. merged prep: NCHW->NHWC + borders + weight pack + bn fold + mlp transpose ---
// blocks [0,12800): nchw2nhwc (2 rows); [12800,17952): borders; [17952,22560): pack_w;
// [22560,22562): prep_bn; [22562,22754): pack_mlp
__global__ __launch_bounds__(256) void prep_all(
    const float* __restrict__ x,
    __hip_bfloat16* __restrict__ xpad, __hip_bfloat16* __restrict__ f1,
    const float* __restrict__ cw, __hip_bfloat16* __restrict__ wpk,
    const float* __restrict__ cb, const float* __restrict__ g,
    const float* __restrict__ bt, const float* __restrict__ mn,
    const float* __restrict__ vr, float* __restrict__ ab,
    const float* __restrict__ w1, const float* __restrict__ w2,
    float* __restrict__ w1t, float* __restrict__ w2t) {
  __shared__ float tile[32][33];
  int bi = blockIdx.x;
  if (bi < 12800) {
    int blk = bi;
    int xt = blk % 5;
    int ct = (blk / 5) & 7;
    int by = blk / 40;
    int b = by / 80, yp = by - (by / 80) * 80;
    int tx = threadIdx.x & 31, ty = threadIdx.x >> 5;
#pragma unroll
    for (int ry = 0; ry < 2; ++ry) {
      int y = yp * 2 + ry;
      const float* src = x + (((size_t)(b * 256 + ct * 32)) * 160 + y) * 160 + xt * 32 + tx;
#pragma unroll
      for (int k = 0; k < 4; k++) tile[ty * 4 + k][tx] = src[(size_t)(ty * 4 + k) * 25600];
      __syncthreads();
      __hip_bfloat16* dst =
          xpad + (((size_t)(b * 162 + y + 1)) * 162 + (xt * 32 + 1)) * 256 + ct * 32 + tx;
#pragma unroll
      for (int k = 0; k < 4; k++) {
        int xx = ty * 4 + k;
        dst[(size_t)xx * 256] = __float2bfloat16(tile[tx][xx]);
      }
      __syncthreads();
    }
  } else if (bi < 17952) {
    int e0 = bi - 12800;
    int buf = e0 / 2576; int rem = e0 - buf * 2576;
    int b = rem / 644;   int e = rem - b * 644;
    int y, xx;
    if (e < 162)      { y = 0;           xx = e; }
    else if (e < 324) { y = 161;         xx = e - 162; }
    else if (e < 484) { y = e - 324 + 1; xx = 0; }
    else              { y = e - 484 + 1; xx = 161; }
    __hip_bfloat16* p = (buf ? f1 : xpad) + (((size_t)b * 162 + y) * 162 + xx) * 256 + threadIdx.x;
    *p = __float2bfloat16(0.f);
  } else if (bi < 22560) {
    int t = (bi - 17952) * 256 + threadIdx.x;
    int ci = t & 255, co = (t >> 8) & 255, rest = t >> 16;
    int tap = rest % 9, lyr = rest / 9;
    int dy = tap / 3, dx = tap - dy * 3;
    float v = cw[((((size_t)lyr * 256 + co) * 256 + ci) * 3 + dy) * 3 + dx];
    wpk[(((size_t)lyr * 9 + tap) * 256 + co) * 256 + ci] = __float2bfloat16(v);
  } else if (bi < 22562) {
    int t = (bi - 22560) * 256 + threadIdx.x;  // 512
    float a = g[t] / sqrtf(vr[t] + 1e-5f);
    ab[t] = a;
    ab[512 + t] = (cb[t] - mn[t]) * a + bt[t];
  } else {
    int t = (bi - 22562) * 256 + threadIdx.x;
    if (t < 32768) {
      int h = t >> 8, k = t & 255;
      w1t[k * 128 + h] = w1[h * 256 + k];
    } else {
      int u = t - 32768;
      int r = u >> 7, k = u & 127;
      w2t[k * 128 + r] = w2[r * 128 + k];
    }
  }
}

// ---------------- 4. conv3x3 + BN + ReLU, implicit GEMM — R5 structure, 32x32x16 MFMA ----------
// BM=128, BN=256 (full N), BK=64; 4 waves, wave-tile 64x128 = 2x4 frags of 32x32.
// 2-barrier K-step; LDS linear, XOR-swizzled via pre-swizzled global source; T1 XCD swizzle.
// 32x32x16 gives same FLOPs at ~17% fewer matrix-pipe cycles (8.07 vs 2x4.85 cy), same LDS bytes.
__global__ __launch_bounds__(256, 2) void conv_bn_relu(
    const __hip_bfloat16* __restrict__ inp, __hip_bfloat16* __restrict__ outp,
    const __hip_bfloat16* __restrict__ wpk,  // [9][256][256] (tap, co, ci)
    const float* __restrict__ alpha, const float* __restrict__ beff) {
  __shared__ __align__(16) short As[128 * 64];   // 16 KB
  __shared__ __align__(16) short Bs[256 * 64];   // 32 KB
  const int t = threadIdx.x;
  // T1: bijective XCD swizzle (grid 800 = 8*100)
  const int mtile = ((blockIdx.x & 7) * 100) + (blockIdx.x >> 3);  // 0..799
  const int l = t & 63;
  const int wv = t >> 6;
  const int half = l >> 5, r5 = l & 31;  // 32x32 frag coords: row/col = r5, k0 = half*8
  const int wm = wv >> 1, wn = wv & 1;   // wave-tile: rows wm*64.., cols wn*128..

  // staging: issue group covers 32 rows; thread t -> row (t>>3), 16B slot (t&7).
  // source pre-swizzle: logical slot = (t&7) ^ (row&7), LDS dest stays linear.
  const int srow = t >> 3;                              // 0..31
  const int koff = (((t & 7) ^ (srow & 7)) << 3);       // logical k-offset (shorts)
  const short* inS = (const short*)inp;
  const short* wS = (const short*)wpk;
  long abase[4];
#pragma unroll
  for (int i = 0; i < 4; i++) {
    int p = mtile * 128 + i * 32 + srow;
    int b = p / 25600; int r = p - b * 25600; int y = r / 160; int x = r - y * 160;
    abase[i] = (((long)b * 162 + y) * 162 + x) * 256 + koff;
  }
  const long bbase = ((long)srow) * 256 + koff;  // + j*8192 for row group j

  f32x16 acc[2][4];
#pragma unroll
  for (int i = 0; i < 2; i++)
#pragma unroll
    for (int j = 0; j < 4; j++)
#pragma unroll
      for (int e = 0; e < 16; e++) acc[i][j][e] = 0.f;

#pragma unroll 1
  for (int u = 0; u < 36; ++u) {
    const int tap = u >> 2, kc = u & 3;
    const int dy = tap / 3, dx = tap - dy * 3;
    const long aoff = ((long)(dy * 162 + dx)) * 256 + kc * 64;
    const long boff = (long)tap * 65536 + kc * 64;
    __syncthreads();  // previous step's LDS reads done
#pragma unroll
    for (int i = 0; i < 4; i++)
      async_ld16(inS + abase[i] + aoff, As + i * 2048 + t * 8);
#pragma unroll
    for (int j = 0; j < 8; j++)
      async_ld16(wS + bbase + boff + (long)j * 8192, Bs + j * 2048 + t * 8);
    __syncthreads();  // drains vmcnt(0): tiles ready
#pragma unroll
    for (int kq = 0; kq < 4; ++kq) {                       // 16-wide k slices
      const int ps = (((kq << 1) | half) ^ (r5 & 7)) << 3; // swizzled 16B slot (shorts)
      s16x8 a2[2], b4[4];
#pragma unroll
      for (int mi = 0; mi < 2; ++mi)
        a2[mi] = *(const s16x8*)&As[(wm * 64 + mi * 32 + r5) * 64 + ps];
#pragma unroll
      for (int ni = 0; ni < 4; ++ni)
        b4[ni] = *(const s16x8*)&Bs[(wn * 128 + ni * 32 + r5) * 64 + ps];
#pragma unroll
      for (int mi = 0; mi < 2; ++mi)
#pragma unroll
        for (int ni = 0; ni < 4; ++ni)
          acc[mi][ni] = __builtin_amdgcn_mfma_f32_32x32x16_bf16(a2[mi], b4[ni], acc[mi][ni], 0, 0, 0);
    }
  }

  // epilogue: y = relu(acc*alpha + beff) -> bf16, padded NHWC
  // C/D layout (32x32): col = r5, row = (reg&3) + 8*(reg>>2) + 4*half  [guide m74/m101]
  float al[4], be_[4];
#pragma unroll
  for (int ni = 0; ni < 4; ++ni) {
    int co = wn * 128 + ni * 32 + r5;
    al[ni] = alpha[co];
    be_[ni] = beff[co];
  }
#pragma unroll
  for (int mi = 0; mi < 2; ++mi) {
#pragma unroll
    for (int rg = 0; rg < 4; ++rg) {
#pragma unroll
      for (int rr = 0; rr < 4; ++rr) {
        int p = mtile * 128 + wm * 64 + mi * 32 + 4 * half + 8 * rg + rr;
        int b = p / 25600; int r = p - b * 25600; int y = r / 160; int x = r - y * 160;
        long ob = (((long)b * 162 + (y + 1)) * 162 + (x + 1)) * 256 + wn * 128;
#pragma unroll
        for (int ni = 0; ni < 4; ++ni) {
          float v = acc[mi][ni][rg * 4 + rr] * al[ni] + be_[ni];
          outp[ob + ni * 32 + r5] = __float2bfloat16(fmaxf(v, 0.f));
        }
      }
    }
  }
}

// ---------------- 5. cumsum along W: bf16 f -> fp32 S, channel-pair vectorized ----------------
// grid 640 (1 row/block), block 128 = channel pairs
__global__ __launch_bounds__(128) void cumsum_w(const __hip_bfloat16* __restrict__ f2,
                                                float* __restrict__ S) {
  int row = blockIdx.x;                            // 0..639
  int b = row / 160, y = row - (row / 160) * 160;
  int cp = threadIdx.x;                            // channel pair index
  const unsigned* src =
      (const unsigned*)((const short*)f2 + (((size_t)b * 162 + y + 1) * 162 + 1) * 256) + cp;
  float2* dst = (float2*)(S + (((size_t)b * 161 + y + 1) * 161) * 256) + cp;
  dst[0] = float2{0.f, 0.f};
  float r0 = 0.f, r1 = 0.f;
  for (int x4 = 0; x4 < 160; x4 += 4) {
    unsigned v[4];
#pragma unroll
    for (int k = 0; k < 4; k++) v[k] = src[(size_t)(x4 + k) * 128];
#pragma unroll
    for (int k = 0; k < 4; k++) {
      r0 += __uint_as_float((v[k] & 0xffffu) << 16);
      r1 += __uint_as_float(v[k] & 0xffff0000u);
      dst[(size_t)(x4 + k + 1) * 128] = float2{r0, r1};
    }
  }
}

// ---------------- 6. cumsum along H in place (16-deep load batching) ----------------
__global__ __launch_bounds__(256) void cumsum_h(float* __restrict__ S) {
  int bi = blockIdx.x;  // 4*161
  int b = bi / 161, q = bi - (bi / 161) * 161;
  int c = threadIdx.x;
  float* col = S + (((size_t)b * 161) * 161 + q) * 256 + c;
  const size_t ys = (size_t)161 * 256;
  col[0] = 0.f;
  float run = 0.f;
  for (int y0 = 1; y0 <= 160; y0 += 16) {
    float v[16];
#pragma unroll
    for (int k = 0; k < 16; k++) v[k] = col[(size_t)(y0 + k) * ys];
#pragma unroll
    for (int k = 0; k < 16; k++) { run += v[k]; col[(size_t)(y0 + k) * ys] = run; }
  }
}

// ---------------- 7. fused ROI 7x7 adaptive pool + MLP + mask + L2 normalize ----------------
__global__ __launch_bounds__(256) void roi_mlp(const float* __restrict__ S,
                                               const float* __restrict__ bbox,
                                               const float* __restrict__ w1t,
                                               const float* __restrict__ b1,
                                               const float* __restrict__ w2t,
                                               const float* __restrict__ b2,
                                               float* __restrict__ out) {
  int bn = blockIdx.x;  // 0..2047
  int b = bn >> 9;
  int t = threadIdx.x;
  __shared__ float pl[256];
  __shared__ float hh[128];
  __shared__ float red[2];

  float bx1 = bbox[bn * 4 + 0], by1 = bbox[bn * 4 + 1];
  float bx2 = bbox[bn * 4 + 2], by2 = bbox[bn * 4 + 3];
  int x1 = min(max((int)floorf(bx1 * 160.f), 0), 160);
  int y1 = min(max((int)floorf(by1 * 160.f), 0), 160);
  int x2 = min(max((int)floorf(bx2 * 160.f), 0), 160);
  int y2 = min(max((int)floorf(by2 * 160.f), 0), 160);
  int vld = (x2 > x1 && y2 > y1) ? 1 : 0;
  int hl = max(y2 - y1, 1), wl = max(x2 - x1, 1);
  int hs[7], he[7], ws_[7], we_[7];
  float rh[7], rw[7];
#pragma unroll
  for (int i = 0; i < 7; i++) {
    hs[i] = y1 + (i * hl) / 7;
    he[i] = y1 + ((i + 1) * hl + 6) / 7;
    rh[i] = 1.f / (float)(he[i] - hs[i]);
    ws_[i] = x1 + (i * wl) / 7;
    we_[i] = x1 + ((i + 1) * wl + 6) / 7;
    rw[i] = 1.f / (float)(we_[i] - ws_[i]);
  }
  const float* Sb = S + (size_t)b * 161 * 161 * 256 + t;
  float acc = 0.f;
#pragma unroll
  for (int i = 0; i < 7; i++) {
    const float* rE = Sb + (size_t)he[i] * (161 * 256);
    const float* rS = Sb + (size_t)hs[i] * (161 * 256);
#pragma unroll
    for (int j = 0; j < 7; j++) {
      size_t qe = (size_t)we_[j] * 256, qs = (size_t)ws_[j] * 256;
      float s = rE[qe] - rS[qe] - rE[qs] + rS[qs];
      acc += s * (rh[i] * rw[j]);
    }
  }
  pl[t] = acc * (1.f / 49.f);
  __syncthreads();

  float a = 0.f;
  if (t < 128) {
    a = b1[t];
#pragma unroll 8
    for (int k = 0; k < 256; k++) a += w1t[k * 128 + t] * pl[k];
    hh[t] = fmaxf(a, 0.f);
  }
  __syncthreads();
  float f = 0.f;
  if (t < 128) {
    f = b2[t];
#pragma unroll 8
    for (int k = 0; k < 128; k++) f += w2t[k * 128 + t] * hh[k];
    if (!vld) f = 0.f;
    float ss = f * f;
#pragma unroll
    for (int off = 32; off > 0; off >>= 1) ss += __shfl_xor(ss, off);
    if ((t & 63) == 0) red[t >> 6] = ss;
  }
  __syncthreads();
  if (t < 128) {
    float nrm = fmaxf(sqrtf(red[0] + red[1]), 1e-12f);
    out[(size_t)bn * 128 + t] = f / nrm;
  }
}

// ---------------- launch ----------------
extern "C" void kernel_launch(void* const* d_in, const int* in_sizes, int n_in,
                              void* d_out, int out_size, void* d_ws, size_t ws_size,
                              hipStream_t stream) {
  const float* x = (const float*)d_in[0];
  const float* bboxes = (const float*)d_in[1];
  const float* conv_w = (const float*)d_in[2];
  const float* conv_b = (const float*)d_in[3];
  const float* bn_g = (const float*)d_in[4];
  const float* bn_b = (const float*)d_in[5];
  const float* bn_m = (const float*)d_in[6];
  const float* bn_v = (const float*)d_in[7];
  const float* w1 = (const float*)d_in[8];
  const float* b1 = (const float*)d_in[9];
  const float* w2 = (const float*)d_in[10];
  const float* b2 = (const float*)d_in[11];

  char* ws = (char*)d_ws;
  const size_t PADB = (size_t)4 * 162 * 162 * 256 * 2;   // 53,747,712 B
  const size_t WPKB = (size_t)2 * 9 * 256 * 256 * 2;     // 2,359,296 B
  const size_t SB = (size_t)4 * 161 * 161 * 256 * 4;     // 106,172,416 B

  __hip_bfloat16* xpad = (__hip_bfloat16*)(ws);
  __hip_bfloat16* f1 = (__hip_bfloat16*)(ws + PADB);
  __hip_bfloat16* wpk = (__hip_bfloat16*)(ws + 2 * PADB);
  float* abuf = (float*)(ws + 2 * PADB + WPKB);
  float* S = (float*)(ws + 2 * PADB + WPKB + 4096);
  float* w1t = (float*)(ws + 2 * PADB + WPKB + 4096 + SB);
  float* w2t = w1t + 32768;

  prep_all<<<22754, 256, 0, stream>>>(x, xpad, f1, conv_w, wpk, conv_b, bn_g, bn_b, bn_m,
                                      bn_v, abuf, w1, w2, w1t, w2t);

  conv_bn_relu<<<800, 256, 0, stream>>>(xpad, f1, wpk, abuf, abuf + 512);
  conv_bn_relu<<<800, 256, 0, stream>>>(f1, xpad, wpk + (size_t)9 * 256 * 256, abuf + 256, abuf + 768);

  cumsum_w<<<640, 128, 0, stream>>>(xpad, S);
  cumsum_h<<<644, 256, 0, stream>>>(S);
  roi_mlp<<<2048, 256, 0, stream>>>(S, bboxes, w1t, b1, w2t, b2, (float*)d_out);
}

// Round 10
// 396.385 us; speedup vs baseline: 1.1184x; 1.1184x over previous
//
#include <hip/hip_runtime.h>
#include <hip/hip_bf16.h>

// ---------------- types ----------------
typedef __attribute__((ext_vector_type(8))) short s16x8;    // 8 bf16 in 4 VGPRs
typedef __attribute__((ext_vector_type(4))) float f32x4;

// B=4, C=256, H=W=160, padded spatial 162, S dims 161, N=512, REID=128

__device__ __forceinline__ void async_ld16(const void* g, void* l) {
  __builtin_amdgcn_global_load_lds(
      (const __attribute__((address_space(1))) void*)g,
      (__attribute__((address_space(3))) void*)l, 16, 0, 0);
}

// ---------------- 0. merged prep: NCHW->NHWC + borders + weight pack + bn fold + mlp transpose ---
// blocks [0,12800): nchw2nhwc (2 rows); [12800,17952): borders; [17952,22560): pack_w;
// [22560,22562): prep_bn; [22562,22754): pack_mlp
__global__ __launch_bounds__(256) void prep_all(
    const float* __restrict__ x,
    __hip_bfloat16* __restrict__ xpad, __hip_bfloat16* __restrict__ f1,
    const float* __restrict__ cw, __hip_bfloat16* __restrict__ wpk,
    const float* __restrict__ cb, const float* __restrict__ g,
    const float* __restrict__ bt, const float* __restrict__ mn,
    const float* __restrict__ vr, float* __restrict__ ab,
    const float* __restrict__ w1, const float* __restrict__ w2,
    float* __restrict__ w1t, float* __restrict__ w2t) {
  __shared__ float tile[32][33];
  int bi = blockIdx.x;
  if (bi < 12800) {
    int blk = bi;
    int xt = blk % 5;
    int ct = (blk / 5) & 7;
    int by = blk / 40;
    int b = by / 80, yp = by - (by / 80) * 80;
    int tx = threadIdx.x & 31, ty = threadIdx.x >> 5;
#pragma unroll
    for (int ry = 0; ry < 2; ++ry) {
      int y = yp * 2 + ry;
      const float* src = x + (((size_t)(b * 256 + ct * 32)) * 160 + y) * 160 + xt * 32 + tx;
#pragma unroll
      for (int k = 0; k < 4; k++) tile[ty * 4 + k][tx] = src[(size_t)(ty * 4 + k) * 25600];
      __syncthreads();
      __hip_bfloat16* dst =
          xpad + (((size_t)(b * 162 + y + 1)) * 162 + (xt * 32 + 1)) * 256 + ct * 32 + tx;
#pragma unroll
      for (int k = 0; k < 4; k++) {
        int xx = ty * 4 + k;
        dst[(size_t)xx * 256] = __float2bfloat16(tile[tx][xx]);
      }
      __syncthreads();
    }
  } else if (bi < 17952) {
    int e0 = bi - 12800;
    int buf = e0 / 2576; int rem = e0 - buf * 2576;
    int b = rem / 644;   int e = rem - b * 644;
    int y, xx;
    if (e < 162)      { y = 0;           xx = e; }
    else if (e < 324) { y = 161;         xx = e - 162; }
    else if (e < 484) { y = e - 324 + 1; xx = 0; }
    else              { y = e - 484 + 1; xx = 161; }
    __hip_bfloat16* p = (buf ? f1 : xpad) + (((size_t)b * 162 + y) * 162 + xx) * 256 + threadIdx.x;
    *p = __float2bfloat16(0.f);
  } else if (bi < 22560) {
    int t = (bi - 17952) * 256 + threadIdx.x;
    int ci = t & 255, co = (t >> 8) & 255, rest = t >> 16;
    int tap = rest % 9, lyr = rest / 9;
    int dy = tap / 3, dx = tap - dy * 3;
    float v = cw[((((size_t)lyr * 256 + co) * 256 + ci) * 3 + dy) * 3 + dx];
    wpk[(((size_t)lyr * 9 + tap) * 256 + co) * 256 + ci] = __float2bfloat16(v);
  } else if (bi < 22562) {
    int t = (bi - 22560) * 256 + threadIdx.x;  // 512
    float a = g[t] / sqrtf(vr[t] + 1e-5f);
    ab[t] = a;
    ab[512 + t] = (cb[t] - mn[t]) * a + bt[t];
  } else {
    int t = (bi - 22562) * 256 + threadIdx.x;
    if (t < 32768) {
      int h = t >> 8, k = t & 255;
      w1t[k * 128 + h] = w1[h * 256 + k];
    } else {
      int u = t - 32768;
      int r = u >> 7, k = u & 127;
      w2t[k * 128 + r] = w2[r * 128 + k];
    }
  }
}

// ---------------- 4. conv3x3 + BN + ReLU, implicit GEMM (bf16 MFMA) — R8-proven structure -------
// BM=128, BN=256 (full N), BK=64; 4 waves, wave-tile 64x128 (4x8 frags of 16x16x32).
// 2-barrier K-step; LDS linear, XOR-swizzled via pre-swizzled global source; T1 XCD swizzle.
__global__ __launch_bounds__(256, 2) void conv_bn_relu(
    const __hip_bfloat16* __restrict__ inp, __hip_bfloat16* __restrict__ outp,
    const __hip_bfloat16* __restrict__ wpk,  // [9][256][256] (tap, co, ci)
    const float* __restrict__ alpha, const float* __restrict__ beff) {
  __shared__ __align__(16) short As[128 * 64];   // 16 KB
  __shared__ __align__(16) short Bs[256 * 64];   // 32 KB
  const int t = threadIdx.x;
  // T1: bijective XCD swizzle (grid 800 = 8*100)
  const int mtile = ((blockIdx.x & 7) * 100) + (blockIdx.x >> 3);  // 0..799
  const int l = t & 63;
  const int wv = t >> 6;
  const int lr = l & 15, lq = l >> 4;
  const int wm = wv >> 1, wn = wv & 1;  // wave-tile: rows wm*64.., cols wn*128..

  // staging: issue group covers 32 rows; thread t -> row (t>>3), 16B slot (t&7).
  // source pre-swizzle: logical slot = (t&7) ^ (row&7), LDS dest stays linear.
  const int srow = t >> 3;                              // 0..31
  const int koff = (((t & 7) ^ (srow & 7)) << 3);       // logical k-offset (shorts)
  const short* inS = (const short*)inp;
  const short* wS = (const short*)wpk;
  long abase[4];
#pragma unroll
  for (int i = 0; i < 4; i++) {
    int p = mtile * 128 + i * 32 + srow;
    int b = p / 25600; int r = p - b * 25600; int y = r / 160; int x = r - y * 160;
    abase[i] = (((long)b * 162 + y) * 162 + x) * 256 + koff;
  }
  const long bbase = ((long)srow) * 256 + koff;  // + j*8192 for row group j

  f32x4 acc[4][8];
#pragma unroll
  for (int i = 0; i < 4; i++)
#pragma unroll
    for (int j = 0; j < 8; j++) acc[i][j] = (f32x4){0.f, 0.f, 0.f, 0.f};

#pragma unroll 1
  for (int u = 0; u < 36; ++u) {
    const int tap = u >> 2, kc = u & 3;
    const int dy = tap / 3, dx = tap - dy * 3;
    const long aoff = ((long)(dy * 162 + dx)) * 256 + kc * 64;
    const long boff = (long)tap * 65536 + kc * 64;
    __syncthreads();  // previous step's LDS reads done
#pragma unroll
    for (int i = 0; i < 4; i++)
      async_ld16(inS + abase[i] + aoff, As + i * 2048 + t * 8);
#pragma unroll
    for (int j = 0; j < 8; j++)
      async_ld16(wS + bbase + boff + (long)j * 8192, Bs + j * 2048 + t * 8);
    __syncthreads();  // drains vmcnt(0): tiles ready
#pragma unroll
    for (int kk = 0; kk < 2; ++kk) {
      const int ps = (((kk << 2) | lq) ^ (lr & 7)) << 3;  // swizzled slot (shorts)
      s16x8 av[4], bv[8];
#pragma unroll
      for (int mi = 0; mi < 4; ++mi)
        av[mi] = *(const s16x8*)&As[(wm * 64 + mi * 16 + lr) * 64 + ps];
#pragma unroll
      for (int ni = 0; ni < 8; ++ni)
        bv[ni] = *(const s16x8*)&Bs[(wn * 128 + ni * 16 + lr) * 64 + ps];
#pragma unroll
      for (int mi = 0; mi < 4; ++mi)
#pragma unroll
        for (int ni = 0; ni < 8; ++ni)
          acc[mi][ni] = __builtin_amdgcn_mfma_f32_16x16x32_bf16(av[mi], bv[ni], acc[mi][ni], 0, 0, 0);
    }
  }

  // epilogue: y = relu(acc*alpha + beff) -> bf16, padded NHWC
  float al[8], be_[8];
#pragma unroll
  for (int ni = 0; ni < 8; ++ni) {
    int co = wn * 128 + ni * 16 + lr;
    al[ni] = alpha[co];
    be_[ni] = beff[co];
  }
#pragma unroll
  for (int mi = 0; mi < 4; ++mi) {
    int prow = mtile * 128 + wm * 64 + mi * 16 + lq * 4;
#pragma unroll
    for (int j = 0; j < 4; ++j) {
      int p = prow + j;
      int b = p / 25600; int r = p - b * 25600; int y = r / 160; int x = r - y * 160;
      long ob = (((long)b * 162 + (y + 1)) * 162 + (x + 1)) * 256 + wn * 128;
#pragma unroll
      for (int ni = 0; ni < 8; ++ni) {
        float v = acc[mi][ni][j] * al[ni] + be_[ni];
        outp[ob + ni * 16 + lr] = __float2bfloat16(fmaxf(v, 0.f));
      }
    }
  }
}

// ---------------- 5. cumsum along W: bf16 f -> fp32 S, channel-pair vectorized, batch-8 ---------
// grid 640 (1 row/block), block 128 = channel pairs
__global__ __launch_bounds__(128) void cumsum_w(const __hip_bfloat16* __restrict__ f2,
                                                float* __restrict__ S) {
  int row = blockIdx.x;                            // 0..639
  int b = row / 160, y = row - (row / 160) * 160;
  int cp = threadIdx.x;                            // channel pair index
  const unsigned* src =
      (const unsigned*)((const short*)f2 + (((size_t)b * 162 + y + 1) * 162 + 1) * 256) + cp;
  float2* dst = (float2*)(S + (((size_t)b * 161 + y + 1) * 161) * 256) + cp;
  dst[0] = float2{0.f, 0.f};
  float r0 = 0.f, r1 = 0.f;
  for (int x8 = 0; x8 < 160; x8 += 8) {
    unsigned v[8];
#pragma unroll
    for (int k = 0; k < 8; k++) v[k] = src[(size_t)(x8 + k) * 128];
#pragma unroll
    for (int k = 0; k < 8; k++) {
      r0 += __uint_as_float((v[k] & 0xffffu) << 16);
      r1 += __uint_as_float(v[k] & 0xffff0000u);
      dst[(size_t)(x8 + k + 1) * 128] = float2{r0, r1};
    }
  }
}

// ---------------- 6. cumsum along H in place (16-deep load batching) ----------------
__global__ __launch_bounds__(256) void cumsum_h(float* __restrict__ S) {
  int bi = blockIdx.x;  // 4*161
  int b = bi / 161, q = bi - (bi / 161) * 161;
  int c = threadIdx.x;
  float* col = S + (((size_t)b * 161) * 161 + q) * 256 + c;
  const size_t ys = (size_t)161 * 256;
  col[0] = 0.f;
  float run = 0.f;
  for (int y0 = 1; y0 <= 160; y0 += 16) {
    float v[16];
#pragma unroll
    for (int k = 0; k < 16; k++) v[k] = col[(size_t)(y0 + k) * ys];
#pragma unroll
    for (int k = 0; k < 16; k++) { run += v[k]; col[(size_t)(y0 + k) * ys] = run; }
  }
}

// ---------------- 7. fused ROI 7x7 adaptive pool + MLP + mask + L2 normalize ----------------
__global__ __launch_bounds__(256) void roi_mlp(const float* __restrict__ S,
                                               const float* __restrict__ bbox,
                                               const float* __restrict__ w1t,
                                               const float* __restrict__ b1,
                                               const float* __restrict__ w2t,
                                               const float* __restrict__ b2,
                                               float* __restrict__ out) {
  int bn = blockIdx.x;  // 0..2047
  int b = bn >> 9;
  int t = threadIdx.x;
  __shared__ float pl[256];
  __shared__ float hh[128];
  __shared__ float red[2];

  float bx1 = bbox[bn * 4 + 0], by1 = bbox[bn * 4 + 1];
  float bx2 = bbox[bn * 4 + 2], by2 = bbox[bn * 4 + 3];
  int x1 = min(max((int)floorf(bx1 * 160.f), 0), 160);
  int y1 = min(max((int)floorf(by1 * 160.f), 0), 160);
  int x2 = min(max((int)floorf(bx2 * 160.f), 0), 160);
  int y2 = min(max((int)floorf(by2 * 160.f), 0), 160);
  int vld = (x2 > x1 && y2 > y1) ? 1 : 0;
  int hl = max(y2 - y1, 1), wl = max(x2 - x1, 1);
  int hs[7], he[7], ws_[7], we_[7];
  float rh[7], rw[7];
#pragma unroll
  for (int i = 0; i < 7; i++) {
    hs[i] = y1 + (i * hl) / 7;
    he[i] = y1 + ((i + 1) * hl + 6) / 7;
    rh[i] = 1.f / (float)(he[i] - hs[i]);
    ws_[i] = x1 + (i * wl) / 7;
    we_[i] = x1 + ((i + 1) * wl + 6) / 7;
    rw[i] = 1.f / (float)(we_[i] - ws_[i]);
  }
  const float* Sb = S + (size_t)b * 161 * 161 * 256 + t;
  float acc = 0.f;
#pragma unroll
  for (int i = 0; i < 7; i++) {
    const float* rE = Sb + (size_t)he[i] * (161 * 256);
    const float* rS = Sb + (size_t)hs[i] * (161 * 256);
#pragma unroll
    for (int j = 0; j < 7; j++) {
      size_t qe = (size_t)we_[j] * 256, qs = (size_t)ws_[j] * 256;
      float s = rE[qe] - rS[qe] - rE[qs] + rS[qs];
      acc += s * (rh[i] * rw[j]);
    }
  }
  pl[t] = acc * (1.f / 49.f);
  __syncthreads();

  float a = 0.f;
  if (t < 128) {
    a = b1[t];
#pragma unroll 8
    for (int k = 0; k < 256; k++) a += w1t[k * 128 + t] * pl[k];
    hh[t] = fmaxf(a, 0.f);
  }
  __syncthreads();
  float f = 0.f;
  if (t < 128) {
    f = b2[t];
#pragma unroll 8
    for (int k = 0; k < 128; k++) f += w2t[k * 128 + t] * hh[k];
    if (!vld) f = 0.f;
    float ss = f * f;
#pragma unroll
    for (int off = 32; off > 0; off >>= 1) ss += __shfl_xor(ss, off);
    if ((t & 63) == 0) red[t >> 6] = ss;
  }
  __syncthreads();
  if (t < 128) {
    float nrm = fmaxf(sqrtf(red[0] + red[1]), 1e-12f);
    out[(size_t)bn * 128 + t] = f / nrm;
  }
}

// ---------------- launch ----------------
extern "C" void kernel_launch(void* const* d_in, const int* in_sizes, int n_in,
                              void* d_out, int out_size, void* d_ws, size_t ws_size,
                              hipStream_t stream) {
  const float* x = (const float*)d_in[0];
  const float* bboxes = (const float*)d_in[1];
  const float* conv_w = (const float*)d_in[2];
  const float* conv_b = (const float*)d_in[3];
  const float* bn_g = (const float*)d_in[4];
  const float* bn_b = (const float*)d_in[5];
  const float* bn_m = (const float*)d_in[6];
  const float* bn_v = (const float*)d_in[7];
  const float* w1 = (const float*)d_in[8];
  const float* b1 = (const float*)d_in[9];
  const float* w2 = (const float*)d_in[10];
  const float* b2 = (const float*)d_in[11];

  char* ws = (char*)d_ws;
  const size_t PADB = (size_t)4 * 162 * 162 * 256 * 2;   // 53,747,712 B
  const size_t WPKB = (size_t)2 * 9 * 256 * 256 * 2;     // 2,359,296 B
  const size_t SB = (size_t)4 * 161 * 161 * 256 * 4;     // 106,172,416 B

  __hip_bfloat16* xpad = (__hip_bfloat16*)(ws);
  __hip_bfloat16* f1 = (__hip_bfloat16*)(ws + PADB);
  __hip_bfloat16* wpk = (__hip_bfloat16*)(ws + 2 * PADB);
  float* abuf = (float*)(ws + 2 * PADB + WPKB);
  float* S = (float*)(ws + 2 * PADB + WPKB + 4096);
  float* w1t = (float*)(ws + 2 * PADB + WPKB + 4096 + SB);
  float* w2t = w1t + 32768;

  prep_all<<<22754, 256, 0, stream>>>(x, xpad, f1, conv_w, wpk, conv_b, bn_g, bn_b, bn_m,
                                      bn_v, abuf, w1, w2, w1t, w2t);

  conv_bn_relu<<<800, 256, 0, stream>>>(xpad, f1, wpk, abuf, abuf + 512);
  conv_bn_relu<<<800, 256, 0, stream>>>(f1, xpad, wpk + (size_t)9 * 256 * 256, abuf + 256, abuf + 768);

  cumsum_w<<<640, 128, 0, stream>>>(xpad, S);
  cumsum_h<<<644, 256, 0, stream>>>(S);
  roi_mlp<<<2048, 256, 0, stream>>>(S, bboxes, w1t, b1, w2t, b2, (float*)d_out);
}